// Round 12
// baseline (473.502 us; speedup 1.0000x reference)
//
#include <hip/hip_runtime.h>
#include <math.h>

typedef _Float16 half4 __attribute__((ext_vector_type(4)));
typedef _Float16 half8 __attribute__((ext_vector_type(8)));
typedef float f32x4 __attribute__((ext_vector_type(4)));

#define GLD16(gptr, lptr)                                                     \
    __builtin_amdgcn_global_load_lds(                                         \
        (const __attribute__((address_space(1))) unsigned int*)(gptr),        \
        (__attribute__((address_space(3))) unsigned int*)(lptr), 16, 0, 0)

namespace {

constexpr int Bb = 4;
constexpr int Tt = 2048;
constexpr int Dd = 1024;
constexpr int BT = Bb * Tt;   // 8192
constexpr int NCH = 16;       // stats chunks = 128-row q-tiles

__device__ inline _Float16 f2h(float f) { return (_Float16)f; }

// ---------------------------------------------------------------------------
// convert X: fp32 [BT][D] -> Xhi, Xlo fp16
// ---------------------------------------------------------------------------
__global__ __launch_bounds__(256) void convert_x_kernel(
    const float* __restrict__ X, _Float16* __restrict__ Xhi, _Float16* __restrict__ Xlo)
{
    const int idx = (blockIdx.x * 256 + threadIdx.x) * 4;
    const float4 v = *(const float4*)(X + idx);
    const float a[4] = {v.x, v.y, v.z, v.w};
    half4 h, l;
#pragma unroll
    for (int i = 0; i < 4; ++i) {
        h[i] = f2h(a[i]);
        l[i] = f2h(a[i] - (float)h[i]);
    }
    *(half4*)(Xhi + idx) = h;
    *(half4*)(Xlo + idx) = l;
}

// ---------------------------------------------------------------------------
// merged weight convert: y=0,1 -> Wq/Wk hi+lo split; y=2 -> Wv transpose (hi)
// ---------------------------------------------------------------------------
__global__ __launch_bounds__(256) void convert_w_kernel(
    const float* __restrict__ Wq, const float* __restrict__ Wk,
    const float* __restrict__ Wv,
    _Float16* __restrict__ Wqh, _Float16* __restrict__ Wql,
    _Float16* __restrict__ Wkh, _Float16* __restrict__ Wkl,
    _Float16* __restrict__ WvTh)
{
    const int y = blockIdx.y;
    if (y < 2) {
        const float* W = y ? Wk : Wq;
        _Float16* Hh = y ? Wkh : Wqh;
        _Float16* Ll = y ? Wkl : Wql;
        const int idx = (blockIdx.x * 256 + threadIdx.x) * 4;
        const float4 v = *(const float4*)(W + idx);
        const float a[4] = {v.x, v.y, v.z, v.w};
        half4 h, l;
#pragma unroll
        for (int i = 0; i < 4; ++i) {
            h[i] = f2h(a[i]);
            l[i] = f2h(a[i] - (float)h[i]);
        }
        *(half4*)(Hh + idx) = h;
        *(half4*)(Ll + idx) = l;
    } else {
        if (blockIdx.x >= 256) return;
        __shared__ float tile[64][65];
        const int n0 = (blockIdx.x & 15) * 64, k0 = (blockIdx.x >> 4) * 64;
        const int tx = threadIdx.x & 63, ty = threadIdx.x >> 6;
#pragma unroll
        for (int i = 0; i < 16; ++i)
            tile[ty + i * 4][tx] = Wv[(size_t)(k0 + ty + i * 4) * Dd + n0 + tx];
        __syncthreads();
#pragma unroll
        for (int i = 0; i < 16; ++i) {
            const float v = tile[tx][ty + i * 4];
            WvTh[(size_t)(n0 + ty + i * 4) * Dd + k0 + tx] = f2h(v);
        }
    }
}

// ---------------------------------------------------------------------------
// GT[s][r] = sum_a Wk[s][a] * Wq[r][a]
// ---------------------------------------------------------------------------
__global__ __launch_bounds__(256) void gt_kernel(
    const _Float16* __restrict__ Wkh, const _Float16* __restrict__ Wkl,
    const _Float16* __restrict__ Wqh, const _Float16* __restrict__ Wql,
    _Float16* __restrict__ GTh, _Float16* __restrict__ GTl)
{
    __shared__ _Float16 Ahl[2][4][512];
    __shared__ _Float16 Bhl[2][4][512];

    const int n0 = blockIdx.x * 64;
    const int m0 = blockIdx.y * 64;
    const int tid = threadIdx.x;
    const int w = tid >> 6, lane = tid & 63;
    const int lr = lane & 15, lq = lane >> 4;
    const int wi = (w >> 1) * 2, wj = (w & 1) * 2;

    f32x4 acc[2][2];
#pragma unroll
    for (int i = 0; i < 2; ++i)
#pragma unroll
        for (int j = 0; j < 2; ++j)
#pragma unroll
            for (int c = 0; c < 4; ++c) acc[i][j][c] = 0.f;

    for (int kk = 0; kk < 1024; kk += 32) {
        __syncthreads();
        {
            const int s = w;
            const size_t ar = (size_t)(m0 + s * 16 + lr) * Dd + kk + lq * 8;
            const size_t br = (size_t)(n0 + s * 16 + lr) * Dd + kk + lq * 8;
            GLD16(Wkh + ar, &Ahl[0][s][0]);
            GLD16(Wkl + ar, &Ahl[1][s][0]);
            GLD16(Wqh + br, &Bhl[0][s][0]);
            GLD16(Wql + br, &Bhl[1][s][0]);
        }
        __syncthreads();
        half8 ah[2], al[2], bh[2], bl[2];
#pragma unroll
        for (int i = 0; i < 2; ++i) {
            ah[i] = *(const half8*)&Ahl[0][wi + i][lane * 8];
            al[i] = *(const half8*)&Ahl[1][wi + i][lane * 8];
        }
#pragma unroll
        for (int j = 0; j < 2; ++j) {
            bh[j] = *(const half8*)&Bhl[0][wj + j][lane * 8];
            bl[j] = *(const half8*)&Bhl[1][wj + j][lane * 8];
        }
#pragma unroll
        for (int i = 0; i < 2; ++i)
#pragma unroll
            for (int j = 0; j < 2; ++j) {
                acc[i][j] = __builtin_amdgcn_mfma_f32_16x16x32_f16(ah[i], bh[j], acc[i][j], 0, 0, 0);
                acc[i][j] = __builtin_amdgcn_mfma_f32_16x16x32_f16(ah[i], bl[j], acc[i][j], 0, 0, 0);
                acc[i][j] = __builtin_amdgcn_mfma_f32_16x16x32_f16(al[i], bh[j], acc[i][j], 0, 0, 0);
            }
    }

#pragma unroll
    for (int i = 0; i < 2; ++i)
#pragma unroll
        for (int r = 0; r < 4; ++r) {
            const int row = m0 + (wi + i) * 16 + lq * 4 + r;
#pragma unroll
            for (int j = 0; j < 2; ++j) {
                const int col = n0 + (wj + j) * 16 + lr;
                const float v = acc[i][j][r];
                const _Float16 h = f2h(v);
                GTh[(size_t)row * Dd + col] = h;
                GTl[(size_t)row * Dd + col] = f2h(v - (float)h);
            }
        }
}

// ---------------------------------------------------------------------------
// tv: XCD-swizzled 1024-block dispatch (kept from R11 — positive evidence).
// All 16 n-tiles of one m-group land on one XCD -> X panel fetched once/XCD.
// tn<8 -> T = X*G (3 products); tn>=8 -> V = X*Wv (1 product).
// ---------------------------------------------------------------------------
__global__ __launch_bounds__(256) void tv_kernel(
    const _Float16* __restrict__ Xhi, const _Float16* __restrict__ Xlo,
    const _Float16* __restrict__ GTh, const _Float16* __restrict__ GTl,
    const _Float16* __restrict__ WvTh,
    _Float16* __restrict__ Thi, _Float16* __restrict__ Tlo,
    _Float16* __restrict__ Vrow)
{
    __shared__ _Float16 smem[16384];   // A planes [0,8K), B planes [8K,16K)

    const int lb = blockIdx.x;
    const int xcd = lb & 7, sl = lb >> 3;      // sl in [0,128)
    const int g = xcd + 8 * (sl >> 4);         // m-group [0,64) pinned to xcd
    const int tn = sl & 15;                    // n-tile [0,16)
    const bool isT = tn < 8;
    const int n0 = (tn & 7) * 128;
    const int m0 = g * 128;

    const int tid = threadIdx.x;
    const int w = tid >> 6, lane = tid & 63;
    const int lr = lane & 15, lq = lane >> 4;
    const int wr = (w >> 1) * 4, wc = (w & 1) * 4;

    f32x4 acc[4][4];
#pragma unroll
    for (int i = 0; i < 4; ++i)
#pragma unroll
        for (int j = 0; j < 4; ++j)
#pragma unroll
            for (int c = 0; c < 4; ++c) acc[i][j][c] = 0.f;

    if (isT) {
        for (int kk = 0; kk < 1024; kk += 32) {
            __syncthreads();
#pragma unroll
            for (int s2 = 0; s2 < 2; ++s2) {
                const int s = w * 2 + s2;
                const size_t ar = (size_t)(m0 + s * 16 + lr) * Dd + kk + lq * 8;
                const size_t br = (size_t)(n0 + s * 16 + lr) * Dd + kk + lq * 8;
                GLD16(Xhi + ar, smem + s * 512);
                GLD16(Xlo + ar, smem + 4096 + s * 512);
                GLD16(GTh + br, smem + 8192 + s * 512);
                GLD16(GTl + br, smem + 12288 + s * 512);
            }
            __syncthreads();
            half8 ah[4], al[4], bh[4], bl[4];
#pragma unroll
            for (int i = 0; i < 4; ++i) {
                ah[i] = *(const half8*)&smem[(wr + i) * 512 + lane * 8];
                al[i] = *(const half8*)&smem[4096 + (wr + i) * 512 + lane * 8];
            }
#pragma unroll
            for (int j = 0; j < 4; ++j) {
                bh[j] = *(const half8*)&smem[8192 + (wc + j) * 512 + lane * 8];
                bl[j] = *(const half8*)&smem[12288 + (wc + j) * 512 + lane * 8];
            }
#pragma unroll
            for (int i = 0; i < 4; ++i)
#pragma unroll
                for (int j = 0; j < 4; ++j) {
                    acc[i][j] = __builtin_amdgcn_mfma_f32_16x16x32_f16(ah[i], bh[j], acc[i][j], 0, 0, 0);
                    acc[i][j] = __builtin_amdgcn_mfma_f32_16x16x32_f16(ah[i], bl[j], acc[i][j], 0, 0, 0);
                    acc[i][j] = __builtin_amdgcn_mfma_f32_16x16x32_f16(al[i], bh[j], acc[i][j], 0, 0, 0);
                }
        }
#pragma unroll
        for (int i = 0; i < 4; ++i)
#pragma unroll
            for (int r = 0; r < 4; ++r) {
                const int row = m0 + (wr + i) * 16 + lq * 4 + r;
#pragma unroll
                for (int j = 0; j < 4; ++j) {
                    const int col = n0 + (wc + j) * 16 + lr;
                    const float v = acc[i][j][r];
                    const _Float16 h = f2h(v);
                    Thi[(size_t)row * Dd + col] = h;
                    Tlo[(size_t)row * Dd + col] = f2h(v - (float)h);
                }
            }
    } else {
        for (int kk = 0; kk < 1024; kk += 32) {
            __syncthreads();
#pragma unroll
            for (int s2 = 0; s2 < 2; ++s2) {
                const int s = w * 2 + s2;
                GLD16(Xhi + (size_t)(m0 + s * 16 + lr) * Dd + kk + lq * 8, smem + s * 512);
                GLD16(WvTh + (size_t)(n0 + s * 16 + lr) * Dd + kk + lq * 8, smem + 8192 + s * 512);
            }
            __syncthreads();
            half8 a[4], b2[4];
#pragma unroll
            for (int i = 0; i < 4; ++i) a[i] = *(const half8*)&smem[(wr + i) * 512 + lane * 8];
#pragma unroll
            for (int j = 0; j < 4; ++j) b2[j] = *(const half8*)&smem[8192 + (wc + j) * 512 + lane * 8];
#pragma unroll
            for (int i = 0; i < 4; ++i)
#pragma unroll
                for (int j = 0; j < 4; ++j)
                    acc[i][j] = __builtin_amdgcn_mfma_f32_16x16x32_f16(a[i], b2[j], acc[i][j], 0, 0, 0);
        }
#pragma unroll
        for (int i = 0; i < 4; ++i)
#pragma unroll
            for (int r = 0; r < 4; ++r) {
                const int row = m0 + (wr + i) * 16 + lq * 4 + r;
#pragma unroll
                for (int j = 0; j < 4; ++j)
                    Vrow[(size_t)row * Dd + n0 + (wc + j) * 16 + lr] = f2h(acc[i][j][r]);
            }
    }
}

// ---------------------------------------------------------------------------
// transpose V + fold invl: Vt[b][d][t] = Vrow[b][t][d] * invl[b][t]
// ---------------------------------------------------------------------------
__global__ __launch_bounds__(256) void transpose_v_kernel(
    const _Float16* __restrict__ Vrow, const float* __restrict__ Lb,
    _Float16* __restrict__ Vt)
{
    __shared__ _Float16 tile[64][78];
    const int d0 = blockIdx.x * 64, t0 = blockIdx.y * 64, b = blockIdx.z;
    const int tx = threadIdx.x & 63, ty = threadIdx.x >> 6;
#pragma unroll
    for (int i = 0; i < 16; ++i)
        tile[ty + i * 4][tx] = Vrow[((size_t)b * Tt + t0 + ty + i * 4) * Dd + d0 + tx];
    __syncthreads();
    const float sc = Lb[(size_t)b * Tt + t0 + tx];
#pragma unroll
    for (int i = 0; i < 16; ++i) {
        const float v = (float)tile[tx][ty + i * 4] * sc;
        Vt[(size_t)b * Dd * Tt + (size_t)(d0 + ty + i * 4) * Tt + t0 + tx] = f2h(v);
    }
}

// ---------------------------------------------------------------------------
// scores + fused stats — exact R8 structure (triangular decode, S store).
// ---------------------------------------------------------------------------
__global__ __launch_bounds__(256) void scores_mfma_kernel(
    const _Float16* __restrict__ Thi, const _Float16* __restrict__ Tlo,
    const _Float16* __restrict__ Xhi, const _Float16* __restrict__ Xlo,
    float* __restrict__ S, float* __restrict__ Pm, float* __restrict__ Pl)
{
    const int t = blockIdx.x;
    int byi = (int)((sqrtf(8.f * t + 1.f) - 1.f) * 0.5f);
    if ((byi + 1) * (byi + 2) / 2 <= t) ++byi;
    if (byi * (byi + 1) / 2 > t) --byi;
    const int bxi = t - byi * (byi + 1) / 2;
    const int b = blockIdx.z;
    const int j0 = bxi * 128, q0 = byi * 128;
    float* Sb = S + (size_t)b * Tt * Tt;

    __shared__ _Float16 Ahl[2][8][512];
    __shared__ _Float16 Bhl[2][8][512];
    const _Float16* Th = Thi + (size_t)b * Tt * Dd;
    const _Float16* Tl = Tlo + (size_t)b * Tt * Dd;
    const _Float16* Xh = Xhi + (size_t)b * Tt * Dd;
    const _Float16* Xl = Xlo + (size_t)b * Tt * Dd;

    const int tid = threadIdx.x;
    const int w = tid >> 6, lane = tid & 63;
    const int lr = lane & 15, lq = lane >> 4;
    const int wr = (w >> 1) * 4, wc = (w & 1) * 4;

    f32x4 acc[4][4];
#pragma unroll
    for (int i = 0; i < 4; ++i)
#pragma unroll
        for (int j = 0; j < 4; ++j)
#pragma unroll
            for (int c = 0; c < 4; ++c) acc[i][j][c] = 0.f;

    for (int kk = 0; kk < 1024; kk += 32) {
        __syncthreads();
#pragma unroll
        for (int s2 = 0; s2 < 2; ++s2) {
            const int s = w * 2 + s2;
            const size_t ar = (size_t)(q0 + s * 16 + lr) * Dd + kk + lq * 8;
            const size_t br = (size_t)(j0 + s * 16 + lr) * Dd + kk + lq * 8;
            GLD16(Th + ar, &Ahl[0][s][0]);
            GLD16(Tl + ar, &Ahl[1][s][0]);
            GLD16(Xh + br, &Bhl[0][s][0]);
            GLD16(Xl + br, &Bhl[1][s][0]);
        }
        __syncthreads();
        half8 ah[4], al[4], bh[4], bl[4];
#pragma unroll
        for (int i = 0; i < 4; ++i) {
            ah[i] = *(const half8*)&Ahl[0][wr + i][lane * 8];
            al[i] = *(const half8*)&Ahl[1][wr + i][lane * 8];
        }
#pragma unroll
        for (int j = 0; j < 4; ++j) {
            bh[j] = *(const half8*)&Bhl[0][wc + j][lane * 8];
            bl[j] = *(const half8*)&Bhl[1][wc + j][lane * 8];
        }
#pragma unroll
        for (int i = 0; i < 4; ++i)
#pragma unroll
            for (int j = 0; j < 4; ++j) {
                acc[i][j] = __builtin_amdgcn_mfma_f32_16x16x32_f16(ah[i], bh[j], acc[i][j], 0, 0, 0);
                acc[i][j] = __builtin_amdgcn_mfma_f32_16x16x32_f16(ah[i], bl[j], acc[i][j], 0, 0, 0);
                acc[i][j] = __builtin_amdgcn_mfma_f32_16x16x32_f16(al[i], bh[j], acc[i][j], 0, 0, 0);
            }
    }

    // masked values + S store
    float sv[4][4][4];
#pragma unroll
    for (int i = 0; i < 4; ++i)
#pragma unroll
        for (int r = 0; r < 4; ++r) {
            const int q = q0 + (wr + i) * 16 + lq * 4 + r;
#pragma unroll
            for (int j = 0; j < 4; ++j) {
                const int jg = j0 + (wc + j) * 16 + lr;
                const float v = (jg <= q) ? floorf(acc[i][j][r] * 0.03125f) : -INFINITY;
                sv[i][j][r] = v;
                Sb[(size_t)q * Tt + jg] = v;
            }
        }

    // fused per-column stats (reuse staging LDS)
    float* red  = (float*)&Ahl[0][0][0];   // [16][128]
    float* colm = red + 2048;              // [128]
    __syncthreads();
    for (int e = tid; e < 2048; e += 256) red[e] = -INFINITY;
    __syncthreads();
    const int rowidx = (w * 4 + lq) * 128;
#pragma unroll
    for (int j = 0; j < 4; ++j) {
        const int c = (wc + j) * 16 + lr;
        float lm = -INFINITY;
#pragma unroll
        for (int i = 0; i < 4; ++i)
#pragma unroll
            for (int r = 0; r < 4; ++r) lm = fmaxf(lm, sv[i][j][r]);
        red[rowidx + c] = lm;
    }
    __syncthreads();
    if (tid < 128) {
        float m = -INFINITY;
#pragma unroll
        for (int e = 0; e < 16; ++e) m = fmaxf(m, red[e * 128 + tid]);
        colm[tid] = m;
    }
    __syncthreads();
    float ls[4];
#pragma unroll
    for (int j = 0; j < 4; ++j) {
        const int c = (wc + j) * 16 + lr;
        const float m = colm[c];
        float s = 0.f;
#pragma unroll
        for (int i = 0; i < 4; ++i)
#pragma unroll
            for (int r = 0; r < 4; ++r)
                if (sv[i][j][r] != -INFINITY) s += __expf(sv[i][j][r] - m);
        ls[j] = s;
    }
    __syncthreads();
    for (int e = tid; e < 2048; e += 256) red[e] = 0.f;
    __syncthreads();
#pragma unroll
    for (int j = 0; j < 4; ++j) red[rowidx + (wc + j) * 16 + lr] = ls[j];
    __syncthreads();
    if (tid < 128) {
        float l = 0.f;
#pragma unroll
        for (int e = 0; e < 16; ++e) l += red[e * 128 + tid];
        const size_t o = ((size_t)b * NCH + byi) * Tt + j0 + tid;
        Pm[o] = colm[tid];
        Pl[o] = l;
    }
}

// ---------------------------------------------------------------------------
// merge NCH=16 partials per column -> m, 1/l  (index-predicated: c >= j>>7)
// ---------------------------------------------------------------------------
__global__ __launch_bounds__(256) void colstats_merge_kernel(
    const float* __restrict__ Pm, const float* __restrict__ Pl,
    float* __restrict__ Mb, float* __restrict__ Lb)
{
    const int j = blockIdx.x * 256 + threadIdx.x;
    const int b = blockIdx.y;
    const int jt = j >> 7;
    float m = -INFINITY, l = 0.f;
    for (int c = jt; c < NCH; ++c) {
        const size_t pidx = ((size_t)b * NCH + c) * Tt + j;
        const float mi = Pm[pidx];
        if (mi == -INFINITY) continue;
        const float li = Pl[pidx];
        if (mi > m) { l = l * __expf(m - mi) + li; m = mi; }
        else        { l += li * __expf(mi - m); }
    }
    Mb[(size_t)b * Tt + j] = m;
    Lb[(size_t)b * Tt + j] = (l > 0.f) ? 1.f / l : 0.f;
}

// ---------------------------------------------------------------------------
// P = exp(S - m[k]) fp16 over LOWER tiles only (0 above diagonal).
// ---------------------------------------------------------------------------
__global__ __launch_bounds__(256) void pmat_kernel(
    const float* __restrict__ S, const float* __restrict__ Mb,
    _Float16* __restrict__ P)
{
    const int t = blockIdx.x;
    int byi = (int)((sqrtf(8.f * t + 1.f) - 1.f) * 0.5f);
    if ((byi + 1) * (byi + 2) / 2 <= t) ++byi;
    if (byi * (byi + 1) / 2 > t) --byi;
    const int bxi = t - byi * (byi + 1) / 2;
    const int b = blockIdx.z;
    const int j0 = bxi * 128, q0 = byi * 128;

    const int tr = threadIdx.x >> 4;            // 0..15
    const int tc = (threadIdx.x & 15) * 8;      // col offset in tile
    const float* mp = Mb + (size_t)b * Tt + j0 + tc;
    float mv[8];
#pragma unroll
    for (int e = 0; e < 8; ++e) mv[e] = mp[e];

#pragma unroll
    for (int it = 0; it < 8; ++it) {
        const int row = q0 + it * 16 + tr;
        const float* Sp = S + (size_t)b * Tt * Tt + (size_t)row * Tt + j0 + tc;
        const float4 s0 = *(const float4*)Sp;
        const float4 s1 = *(const float4*)(Sp + 4);
        const float sa[8] = {s0.x, s0.y, s0.z, s0.w, s1.x, s1.y, s1.z, s1.w};
        half8 out;
#pragma unroll
        for (int e = 0; e < 8; ++e) {
            const int jg = j0 + tc + e;
            out[e] = (jg <= row) ? f2h(__expf(sa[e] - mv[e])) : (_Float16)0.f;
        }
        *(half8*)(P + (size_t)b * Tt * Tt + (size_t)row * Tt + j0 + tc) = out;
    }
}

// ---------------------------------------------------------------------------
// context = P @ Vscaled.  Single-product fp16 MFMA, causal k-truncation.
// ---------------------------------------------------------------------------
__global__ __launch_bounds__(256) void context_mfma_kernel(
    const _Float16* __restrict__ P, const _Float16* __restrict__ Vt,
    float* __restrict__ Out)
{
    __shared__ _Float16 Al[8][512];
    __shared__ _Float16 Bl[8][512];

    const int bx = blockIdx.x;
    const int by = (int)gridDim.y - 1 - blockIdx.y;  // heavy q-blocks first
    const int b  = blockIdx.z;
    const int d0 = bx * 128;
    const int q0 = by * 128;
    const _Float16* Pb = P + (size_t)b * Tt * Tt;
    const _Float16* Vb = Vt + (size_t)b * Dd * Tt;
    float* Ob = Out + (size_t)b * Tt * Dd;

    const int tid = threadIdx.x;
    const int w = tid >> 6, lane = tid & 63;
    const int lr = lane & 15, lq = lane >> 4;
    const int wr = (w >> 1) * 4, wc = (w & 1) * 4;

    f32x4 acc[4][4];
#pragma unroll
    for (int i = 0; i < 4; ++i)
#pragma unroll
        for (int j = 0; j < 4; ++j)
#pragma unroll
            for (int c = 0; c < 4; ++c) acc[i][j][c] = 0.f;

    const int kmax = q0 + 128;
    for (int k0 = 0; k0 < kmax; k0 += 32) {
        __syncthreads();
#pragma unroll
        for (int s2 = 0; s2 < 2; ++s2) {
            const int s = w * 2 + s2;
            GLD16(Pb + (size_t)(q0 + s * 16 + lr) * Tt + k0 + lq * 8, &Al[s][0]);
            GLD16(Vb + (size_t)(d0 + s * 16 + lr) * Tt + k0 + lq * 8, &Bl[s][0]);
        }
        __syncthreads();
        half8 a[4], b2[4];
#pragma unroll
        for (int i = 0; i < 4; ++i) a[i] = *(const half8*)&Al[wr + i][lane * 8];
#pragma unroll
        for (int j = 0; j < 4; ++j) b2[j] = *(const half8*)&Bl[wc + j][lane * 8];
#pragma unroll
        for (int i = 0; i < 4; ++i)
#pragma unroll
            for (int j = 0; j < 4; ++j)
                acc[i][j] = __builtin_amdgcn_mfma_f32_16x16x32_f16(a[i], b2[j], acc[i][j], 0, 0, 0);
    }

#pragma unroll
    for (int i = 0; i < 4; ++i)
#pragma unroll
        for (int r = 0; r < 4; ++r) {
            const int row = q0 + (wr + i) * 16 + lq * 4 + r;
#pragma unroll
            for (int j = 0; j < 4; ++j)
                Ob[(size_t)row * Dd + d0 + (wc + j) * 16 + lr] = acc[i][j][r];
        }
}

}  // namespace

extern "C" void kernel_launch(void* const* d_in, const int* in_sizes, int n_in,
                              void* d_out, int out_size, void* d_ws, size_t ws_size,
                              hipStream_t stream)
{
    const float* X  = (const float*)d_in[0];
    const float* Wq = (const float*)d_in[1];
    const float* Wk = (const float*)d_in[2];
    const float* Wv = (const float*)d_in[3];

    char* ws = (char*)d_ws;
    const size_t MB = 1024 * 1024;
    _Float16* Xhi  = (_Float16*)ws;
    _Float16* Xlo  = (_Float16*)(ws + 16 * MB);
    _Float16* Wqh  = (_Float16*)(ws + 32 * MB);
    _Float16* Wql  = (_Float16*)(ws + 34 * MB);
    _Float16* Wkh  = (_Float16*)(ws + 36 * MB);
    _Float16* Wkl  = (_Float16*)(ws + 38 * MB);
    _Float16* WvTh = (_Float16*)(ws + 40 * MB);
    _Float16* GTh  = (_Float16*)(ws + 44 * MB);
    _Float16* GTl  = (_Float16*)(ws + 46 * MB);
    _Float16* Thi  = (_Float16*)(ws + 48 * MB);
    _Float16* Tlo  = (_Float16*)(ws + 64 * MB);
    _Float16* P    = Thi;                             // overlay after scores (32 MB)
    _Float16* Vt   = (_Float16*)(ws + 80 * MB);
    _Float16* Vrow = (_Float16*)(ws + 96 * MB);
    float*    S    = (float*)(ws + 112 * MB);         // 64 MB
    float*    Mb   = (float*)(ws + 176 * MB);
    float*    Lb   = Mb + (size_t)Bb * Tt;
    float*    Pm   = Lb + (size_t)Bb * Tt;
    float*    Pl   = Pm + (size_t)Bb * NCH * Tt;
    float*    Out  = (float*)d_out;

    convert_x_kernel<<<BT * Dd / 1024, 256, 0, stream>>>(X, Xhi, Xlo);
    convert_w_kernel<<<dim3(Dd * Dd / 1024, 3), 256, 0, stream>>>(
        Wq, Wk, Wv, Wqh, Wql, Wkh, Wkl, WvTh);
    gt_kernel<<<dim3(16, 16), 256, 0, stream>>>(Wkh, Wkl, Wqh, Wql, GTh, GTl);
    tv_kernel<<<dim3(1024), 256, 0, stream>>>(Xhi, Xlo, GTh, GTl, WvTh, Thi, Tlo, Vrow);
    scores_mfma_kernel<<<dim3(136, 1, Bb), 256, 0, stream>>>(Thi, Tlo, Xhi, Xlo, S, Pm, Pl);
    colstats_merge_kernel<<<dim3(Tt / 256, Bb), 256, 0, stream>>>(Pm, Pl, Mb, Lb);
    transpose_v_kernel<<<dim3(Dd / 64, Tt / 64, Bb), 256, 0, stream>>>(Vrow, Lb, Vt);
    pmat_kernel<<<dim3(136, 1, Bb), 256, 0, stream>>>(S, Mb, P);
    context_mfma_kernel<<<dim3(Dd / 128, Tt / 128, Bb), 256, 0, stream>>>(P, Vt, Out);
}

// Round 13
// 457.297 us; speedup vs baseline: 1.0354x; 1.0354x over previous
//
#include <hip/hip_runtime.h>
#include <math.h>

typedef _Float16 half4 __attribute__((ext_vector_type(4)));
typedef _Float16 half8 __attribute__((ext_vector_type(8)));
typedef float f32x4 __attribute__((ext_vector_type(4)));

#define GLD16(gptr, lptr)                                                     \
    __builtin_amdgcn_global_load_lds(                                         \
        (const __attribute__((address_space(1))) unsigned int*)(gptr),        \
        (__attribute__((address_space(3))) unsigned int*)(lptr), 16, 0, 0)

namespace {

constexpr int Bb = 4;
constexpr int Tt = 2048;
constexpr int Dd = 1024;
constexpr int BT = Bb * Tt;   // 8192
constexpr int NCH = 16;       // stats chunks = 128-row q-tiles

__device__ inline _Float16 f2h(float f) { return (_Float16)f; }

// ---------------------------------------------------------------------------
// convert X: fp32 [BT][D] -> Xhi, Xlo fp16
// ---------------------------------------------------------------------------
__global__ __launch_bounds__(256) void convert_x_kernel(
    const float* __restrict__ X, _Float16* __restrict__ Xhi, _Float16* __restrict__ Xlo)
{
    const int idx = (blockIdx.x * 256 + threadIdx.x) * 4;
    const float4 v = *(const float4*)(X + idx);
    const float a[4] = {v.x, v.y, v.z, v.w};
    half4 h, l;
#pragma unroll
    for (int i = 0; i < 4; ++i) {
        h[i] = f2h(a[i]);
        l[i] = f2h(a[i] - (float)h[i]);
    }
    *(half4*)(Xhi + idx) = h;
    *(half4*)(Xlo + idx) = l;
}

// ---------------------------------------------------------------------------
// convert Wq,Wk (NO transpose): fp32 [r][a] -> hi/lo fp16 [r][a]
// ---------------------------------------------------------------------------
__global__ __launch_bounds__(256) void convert_wqk_kernel(
    const float* __restrict__ Wq, const float* __restrict__ Wk,
    _Float16* __restrict__ Wqh, _Float16* __restrict__ Wql,
    _Float16* __restrict__ Wkh, _Float16* __restrict__ Wkl)
{
    const int mat = blockIdx.y;
    const float* W = mat ? Wk : Wq;
    _Float16* Hh = mat ? Wkh : Wqh;
    _Float16* Ll = mat ? Wkl : Wql;
    const int idx = (blockIdx.x * 256 + threadIdx.x) * 4;
    const float4 v = *(const float4*)(W + idx);
    const float a[4] = {v.x, v.y, v.z, v.w};
    half4 h, l;
#pragma unroll
    for (int i = 0; i < 4; ++i) {
        h[i] = f2h(a[i]);
        l[i] = f2h(a[i] - (float)h[i]);
    }
    *(half4*)(Hh + idx) = h;
    *(half4*)(Ll + idx) = l;
}

// ---------------------------------------------------------------------------
// convert+transpose Wv: fp32 Wv[r][n] -> WvT[n][r] hi fp16
// ---------------------------------------------------------------------------
__global__ __launch_bounds__(256) void convert_wv_kernel(
    const float* __restrict__ Wv, _Float16* __restrict__ WvTh)
{
    __shared__ float tile[64][65];
    const int n0 = blockIdx.x * 64, k0 = blockIdx.y * 64;
    const int tx = threadIdx.x & 63, ty = threadIdx.x >> 6;
#pragma unroll
    for (int i = 0; i < 16; ++i)
        tile[ty + i * 4][tx] = Wv[(size_t)(k0 + ty + i * 4) * Dd + n0 + tx];
    __syncthreads();
#pragma unroll
    for (int i = 0; i < 16; ++i) {
        const float v = tile[tx][ty + i * 4];
        WvTh[(size_t)(n0 + ty + i * 4) * Dd + k0 + tx] = f2h(v);
    }
}

// ---------------------------------------------------------------------------
// GT[s][r] = sum_a Wk[s][a] * Wq[r][a]
// ---------------------------------------------------------------------------
__global__ __launch_bounds__(256) void gt_kernel(
    const _Float16* __restrict__ Wkh, const _Float16* __restrict__ Wkl,
    const _Float16* __restrict__ Wqh, const _Float16* __restrict__ Wql,
    _Float16* __restrict__ GTh, _Float16* __restrict__ GTl)
{
    __shared__ _Float16 Ahl[2][4][512];
    __shared__ _Float16 Bhl[2][4][512];

    const int n0 = blockIdx.x * 64;
    const int m0 = blockIdx.y * 64;
    const int tid = threadIdx.x;
    const int w = tid >> 6, lane = tid & 63;
    const int lr = lane & 15, lq = lane >> 4;
    const int wi = (w >> 1) * 2, wj = (w & 1) * 2;

    f32x4 acc[2][2];
#pragma unroll
    for (int i = 0; i < 2; ++i)
#pragma unroll
        for (int j = 0; j < 2; ++j)
#pragma unroll
            for (int c = 0; c < 4; ++c) acc[i][j][c] = 0.f;

    for (int kk = 0; kk < 1024; kk += 32) {
        __syncthreads();
        {
            const int s = w;
            const size_t ar = (size_t)(m0 + s * 16 + lr) * Dd + kk + lq * 8;
            const size_t br = (size_t)(n0 + s * 16 + lr) * Dd + kk + lq * 8;
            GLD16(Wkh + ar, &Ahl[0][s][0]);
            GLD16(Wkl + ar, &Ahl[1][s][0]);
            GLD16(Wqh + br, &Bhl[0][s][0]);
            GLD16(Wql + br, &Bhl[1][s][0]);
        }
        __syncthreads();
        half8 ah[2], al[2], bh[2], bl[2];
#pragma unroll
        for (int i = 0; i < 2; ++i) {
            ah[i] = *(const half8*)&Ahl[0][wi + i][lane * 8];
            al[i] = *(const half8*)&Ahl[1][wi + i][lane * 8];
        }
#pragma unroll
        for (int j = 0; j < 2; ++j) {
            bh[j] = *(const half8*)&Bhl[0][wj + j][lane * 8];
            bl[j] = *(const half8*)&Bhl[1][wj + j][lane * 8];
        }
#pragma unroll
        for (int i = 0; i < 2; ++i)
#pragma unroll
            for (int j = 0; j < 2; ++j) {
                acc[i][j] = __builtin_amdgcn_mfma_f32_16x16x32_f16(ah[i], bh[j], acc[i][j], 0, 0, 0);
                acc[i][j] = __builtin_amdgcn_mfma_f32_16x16x32_f16(ah[i], bl[j], acc[i][j], 0, 0, 0);
                acc[i][j] = __builtin_amdgcn_mfma_f32_16x16x32_f16(al[i], bh[j], acc[i][j], 0, 0, 0);
            }
    }

#pragma unroll
    for (int i = 0; i < 2; ++i)
#pragma unroll
        for (int r = 0; r < 4; ++r) {
            const int row = m0 + (wi + i) * 16 + lq * 4 + r;
#pragma unroll
            for (int j = 0; j < 2; ++j) {
                const int col = n0 + (wj + j) * 16 + lr;
                const float v = acc[i][j][r];
                const _Float16 h = f2h(v);
                GTh[(size_t)row * Dd + col] = h;
                GTl[(size_t)row * Dd + col] = f2h(v - (float)h);
            }
        }
}

// ---------------------------------------------------------------------------
// T = X*G (3 products, B-rows = GT), out T hi/lo.  128x128 tile template.
// ---------------------------------------------------------------------------
__global__ __launch_bounds__(256) void t_kernel(
    const _Float16* __restrict__ Xhi, const _Float16* __restrict__ Xlo,
    const _Float16* __restrict__ GTh, const _Float16* __restrict__ GTl,
    _Float16* __restrict__ Thi, _Float16* __restrict__ Tlo)
{
    __shared__ _Float16 Ahl[2][8][512];
    __shared__ _Float16 Bhl[2][8][512];

    const int n0 = blockIdx.x * 128;
    const int m0 = blockIdx.y * 128;
    const int tid = threadIdx.x;
    const int w = tid >> 6, lane = tid & 63;
    const int lr = lane & 15, lq = lane >> 4;
    const int wr = (w >> 1) * 4, wc = (w & 1) * 4;

    f32x4 acc[4][4];
#pragma unroll
    for (int i = 0; i < 4; ++i)
#pragma unroll
        for (int j = 0; j < 4; ++j)
#pragma unroll
            for (int c = 0; c < 4; ++c) acc[i][j][c] = 0.f;

    for (int kk = 0; kk < 1024; kk += 32) {
        __syncthreads();
#pragma unroll
        for (int s2 = 0; s2 < 2; ++s2) {
            const int s = w * 2 + s2;
            const size_t ar = (size_t)(m0 + s * 16 + lr) * Dd + kk + lq * 8;
            const size_t br = (size_t)(n0 + s * 16 + lr) * Dd + kk + lq * 8;
            GLD16(Xhi + ar, &Ahl[0][s][0]);
            GLD16(Xlo + ar, &Ahl[1][s][0]);
            GLD16(GTh + br, &Bhl[0][s][0]);
            GLD16(GTl + br, &Bhl[1][s][0]);
        }
        __syncthreads();
        half8 ah[4], al[4], bh[4], bl[4];
#pragma unroll
        for (int i = 0; i < 4; ++i) {
            ah[i] = *(const half8*)&Ahl[0][wr + i][lane * 8];
            al[i] = *(const half8*)&Ahl[1][wr + i][lane * 8];
        }
#pragma unroll
        for (int j = 0; j < 4; ++j) {
            bh[j] = *(const half8*)&Bhl[0][wc + j][lane * 8];
            bl[j] = *(const half8*)&Bhl[1][wc + j][lane * 8];
        }
#pragma unroll
        for (int i = 0; i < 4; ++i)
#pragma unroll
            for (int j = 0; j < 4; ++j) {
                acc[i][j] = __builtin_amdgcn_mfma_f32_16x16x32_f16(ah[i], bh[j], acc[i][j], 0, 0, 0);
                acc[i][j] = __builtin_amdgcn_mfma_f32_16x16x32_f16(ah[i], bl[j], acc[i][j], 0, 0, 0);
                acc[i][j] = __builtin_amdgcn_mfma_f32_16x16x32_f16(al[i], bh[j], acc[i][j], 0, 0, 0);
            }
    }
#pragma unroll
    for (int i = 0; i < 4; ++i)
#pragma unroll
        for (int r = 0; r < 4; ++r) {
            const int row = m0 + (wr + i) * 16 + lq * 4 + r;
#pragma unroll
            for (int j = 0; j < 4; ++j) {
                const int col = n0 + (wc + j) * 16 + lr;
                const float v = acc[i][j][r];
                const _Float16 h = f2h(v);
                Thi[(size_t)row * Dd + col] = h;
                Tlo[(size_t)row * Dd + col] = f2h(v - (float)h);
            }
        }
}

// ---------------------------------------------------------------------------
// V = X*Wv (single hi product), out fp16 row-major.
// ---------------------------------------------------------------------------
__global__ __launch_bounds__(256) void v_kernel(
    const _Float16* __restrict__ Xhi, const _Float16* __restrict__ WvTh,
    _Float16* __restrict__ Vrow)
{
    __shared__ _Float16 Al[8][512];
    __shared__ _Float16 Bl[8][512];

    const int n0 = blockIdx.x * 128;
    const int m0 = blockIdx.y * 128;
    const int tid = threadIdx.x;
    const int w = tid >> 6, lane = tid & 63;
    const int lr = lane & 15, lq = lane >> 4;
    const int wr = (w >> 1) * 4, wc = (w & 1) * 4;

    f32x4 acc[4][4];
#pragma unroll
    for (int i = 0; i < 4; ++i)
#pragma unroll
        for (int j = 0; j < 4; ++j)
#pragma unroll
            for (int c = 0; c < 4; ++c) acc[i][j][c] = 0.f;

    for (int kk = 0; kk < 1024; kk += 32) {
        __syncthreads();
#pragma unroll
        for (int s2 = 0; s2 < 2; ++s2) {
            const int s = w * 2 + s2;
            GLD16(Xhi + (size_t)(m0 + s * 16 + lr) * Dd + kk + lq * 8, &Al[s][0]);
            GLD16(WvTh + (size_t)(n0 + s * 16 + lr) * Dd + kk + lq * 8, &Bl[s][0]);
        }
        __syncthreads();
        half8 a[4], b2[4];
#pragma unroll
        for (int i = 0; i < 4; ++i) a[i] = *(const half8*)&Al[wr + i][lane * 8];
#pragma unroll
        for (int j = 0; j < 4; ++j) b2[j] = *(const half8*)&Bl[wc + j][lane * 8];
#pragma unroll
        for (int i = 0; i < 4; ++i)
#pragma unroll
            for (int j = 0; j < 4; ++j)
                acc[i][j] = __builtin_amdgcn_mfma_f32_16x16x32_f16(a[i], b2[j], acc[i][j], 0, 0, 0);
    }
#pragma unroll
    for (int i = 0; i < 4; ++i)
#pragma unroll
        for (int r = 0; r < 4; ++r) {
            const int row = m0 + (wr + i) * 16 + lq * 4 + r;
#pragma unroll
            for (int j = 0; j < 4; ++j)
                Vrow[(size_t)row * Dd + n0 + (wc + j) * 16 + lr] = f2h(acc[i][j][r]);
        }
}

// ---------------------------------------------------------------------------
// transpose V + fold invl: Vt[b][d][t] = Vrow[b][t][d] * invl[b][t]
// (runs AFTER colstats_merge)
// ---------------------------------------------------------------------------
__global__ __launch_bounds__(256) void transpose_v_kernel(
    const _Float16* __restrict__ Vrow, const float* __restrict__ Lb,
    _Float16* __restrict__ Vt)
{
    __shared__ _Float16 tile[64][78];
    const int d0 = blockIdx.x * 64, t0 = blockIdx.y * 64, b = blockIdx.z;
    const int tx = threadIdx.x & 63, ty = threadIdx.x >> 6;
#pragma unroll
    for (int i = 0; i < 16; ++i)
        tile[ty + i * 4][tx] = Vrow[((size_t)b * Tt + t0 + ty + i * 4) * Dd + d0 + tx];
    __syncthreads();
    const float sc = Lb[(size_t)b * Tt + t0 + tx];
#pragma unroll
    for (int i = 0; i < 16; ++i) {
        const float v = (float)tile[tx][ty + i * 4] * sc;
        Vt[(size_t)b * Dd * Tt + (size_t)(d0 + ty + i * 4) * Tt + t0 + tx] = f2h(v);
    }
}

// ---------------------------------------------------------------------------
// scores + FUSED column stats.  Lower-triangle tiles; per tile writes
// S (fp32) and per-column partial (max, sumexp) at chunk index byi.
// ---------------------------------------------------------------------------
__global__ __launch_bounds__(256) void scores_mfma_kernel(
    const _Float16* __restrict__ Thi, const _Float16* __restrict__ Tlo,
    const _Float16* __restrict__ Xhi, const _Float16* __restrict__ Xlo,
    float* __restrict__ S, float* __restrict__ Pm, float* __restrict__ Pl)
{
    const int t = blockIdx.x;
    int byi = (int)((sqrtf(8.f * t + 1.f) - 1.f) * 0.5f);
    if ((byi + 1) * (byi + 2) / 2 <= t) ++byi;
    if (byi * (byi + 1) / 2 > t) --byi;
    const int bxi = t - byi * (byi + 1) / 2;
    const int b = blockIdx.z;
    const int j0 = bxi * 128, q0 = byi * 128;
    float* Sb = S + (size_t)b * Tt * Tt;

    __shared__ _Float16 Ahl[2][8][512];
    __shared__ _Float16 Bhl[2][8][512];
    const _Float16* Th = Thi + (size_t)b * Tt * Dd;
    const _Float16* Tl = Tlo + (size_t)b * Tt * Dd;
    const _Float16* Xh = Xhi + (size_t)b * Tt * Dd;
    const _Float16* Xl = Xlo + (size_t)b * Tt * Dd;

    const int tid = threadIdx.x;
    const int w = tid >> 6, lane = tid & 63;
    const int lr = lane & 15, lq = lane >> 4;
    const int wr = (w >> 1) * 4, wc = (w & 1) * 4;

    f32x4 acc[4][4];
#pragma unroll
    for (int i = 0; i < 4; ++i)
#pragma unroll
        for (int j = 0; j < 4; ++j)
#pragma unroll
            for (int c = 0; c < 4; ++c) acc[i][j][c] = 0.f;

    for (int kk = 0; kk < 1024; kk += 32) {
        __syncthreads();
#pragma unroll
        for (int s2 = 0; s2 < 2; ++s2) {
            const int s = w * 2 + s2;
            const size_t ar = (size_t)(q0 + s * 16 + lr) * Dd + kk + lq * 8;
            const size_t br = (size_t)(j0 + s * 16 + lr) * Dd + kk + lq * 8;
            GLD16(Th + ar, &Ahl[0][s][0]);
            GLD16(Tl + ar, &Ahl[1][s][0]);
            GLD16(Xh + br, &Bhl[0][s][0]);
            GLD16(Xl + br, &Bhl[1][s][0]);
        }
        __syncthreads();
        half8 ah[4], al[4], bh[4], bl[4];
#pragma unroll
        for (int i = 0; i < 4; ++i) {
            ah[i] = *(const half8*)&Ahl[0][wr + i][lane * 8];
            al[i] = *(const half8*)&Ahl[1][wr + i][lane * 8];
        }
#pragma unroll
        for (int j = 0; j < 4; ++j) {
            bh[j] = *(const half8*)&Bhl[0][wc + j][lane * 8];
            bl[j] = *(const half8*)&Bhl[1][wc + j][lane * 8];
        }
#pragma unroll
        for (int i = 0; i < 4; ++i)
#pragma unroll
            for (int j = 0; j < 4; ++j) {
                acc[i][j] = __builtin_amdgcn_mfma_f32_16x16x32_f16(ah[i], bh[j], acc[i][j], 0, 0, 0);
                acc[i][j] = __builtin_amdgcn_mfma_f32_16x16x32_f16(ah[i], bl[j], acc[i][j], 0, 0, 0);
                acc[i][j] = __builtin_amdgcn_mfma_f32_16x16x32_f16(al[i], bh[j], acc[i][j], 0, 0, 0);
            }
    }

    // masked values + S store
    float sv[4][4][4];
#pragma unroll
    for (int i = 0; i < 4; ++i)
#pragma unroll
        for (int r = 0; r < 4; ++r) {
            const int q = q0 + (wr + i) * 16 + lq * 4 + r;
#pragma unroll
            for (int j = 0; j < 4; ++j) {
                const int jg = j0 + (wc + j) * 16 + lr;
                const float v = (jg <= q) ? floorf(acc[i][j][r] * 0.03125f) : -INFINITY;
                sv[i][j][r] = v;
                Sb[(size_t)q * Tt + jg] = v;
            }
        }

    // fused per-column stats (reuse staging LDS: 16x128 partials + 128 colmax)
    float* red  = (float*)&Ahl[0][0][0];   // [16][128]
    float* colm = red + 2048;              // [128]
    __syncthreads();
    for (int e = tid; e < 2048; e += 256) red[e] = -INFINITY;
    __syncthreads();
    const int rowidx = (w * 4 + lq) * 128;
#pragma unroll
    for (int j = 0; j < 4; ++j) {
        const int c = (wc + j) * 16 + lr;
        float lm = -INFINITY;
#pragma unroll
        for (int i = 0; i < 4; ++i)
#pragma unroll
            for (int r = 0; r < 4; ++r) lm = fmaxf(lm, sv[i][j][r]);
        red[rowidx + c] = lm;
    }
    __syncthreads();
    if (tid < 128) {
        float m = -INFINITY;
#pragma unroll
        for (int e = 0; e < 16; ++e) m = fmaxf(m, red[e * 128 + tid]);
        colm[tid] = m;
    }
    __syncthreads();
    float ls[4];
#pragma unroll
    for (int j = 0; j < 4; ++j) {
        const int c = (wc + j) * 16 + lr;
        const float m = colm[c];
        float s = 0.f;
#pragma unroll
        for (int i = 0; i < 4; ++i)
#pragma unroll
            for (int r = 0; r < 4; ++r)
                if (sv[i][j][r] != -INFINITY) s += __expf(sv[i][j][r] - m);
        ls[j] = s;
    }
    __syncthreads();
    for (int e = tid; e < 2048; e += 256) red[e] = 0.f;
    __syncthreads();
#pragma unroll
    for (int j = 0; j < 4; ++j) red[rowidx + (wc + j) * 16 + lr] = ls[j];
    __syncthreads();
    if (tid < 128) {
        float l = 0.f;
#pragma unroll
        for (int e = 0; e < 16; ++e) l += red[e * 128 + tid];
        const size_t o = ((size_t)b * NCH + byi) * Tt + j0 + tid;
        Pm[o] = colm[tid];
        Pl[o] = l;
    }
}

// ---------------------------------------------------------------------------
// merge NCH=16 partials per column -> m, 1/l  (index-predicated: c >= j>>7)
// ---------------------------------------------------------------------------
__global__ __launch_bounds__(256) void colstats_merge_kernel(
    const float* __restrict__ Pm, const float* __restrict__ Pl,
    float* __restrict__ Mb, float* __restrict__ Lb)
{
    const int j = blockIdx.x * 256 + threadIdx.x;
    const int b = blockIdx.y;
    const int jt = j >> 7;
    float m = -INFINITY, l = 0.f;
    for (int c = jt; c < NCH; ++c) {
        const size_t pidx = ((size_t)b * NCH + c) * Tt + j;
        const float mi = Pm[pidx];
        if (mi == -INFINITY) continue;
        const float li = Pl[pidx];
        if (mi > m) { l = l * __expf(m - mi) + li; m = mi; }
        else        { l += li * __expf(mi - m); }
    }
    Mb[(size_t)b * Tt + j] = m;
    Lb[(size_t)b * Tt + j] = (l > 0.f) ? 1.f / l : 0.f;
}

// ---------------------------------------------------------------------------
// P = exp(S - m[k]) fp16 over LOWER tiles only (diagonal: 0 above diag).
// ---------------------------------------------------------------------------
__global__ __launch_bounds__(256) void pmat_kernel(
    const float* __restrict__ S, const float* __restrict__ Mb,
    _Float16* __restrict__ P)
{
    const int t = blockIdx.x;
    int byi = (int)((sqrtf(8.f * t + 1.f) - 1.f) * 0.5f);
    if ((byi + 1) * (byi + 2) / 2 <= t) ++byi;
    if (byi * (byi + 1) / 2 > t) --byi;
    const int bxi = t - byi * (byi + 1) / 2;
    const int b = blockIdx.z;
    const int j0 = bxi * 128, q0 = byi * 128;

    const int tr = threadIdx.x >> 4;            // 0..15
    const int tc = (threadIdx.x & 15) * 8;      // col offset in tile
    const float* mp = Mb + (size_t)b * Tt + j0 + tc;
    float mv[8];
#pragma unroll
    for (int e = 0; e < 8; ++e) mv[e] = mp[e];

#pragma unroll
    for (int it = 0; it < 8; ++it) {
        const int row = q0 + it * 16 + tr;
        const float* Sp = S + (size_t)b * Tt * Tt + (size_t)row * Tt + j0 + tc;
        const float4 s0 = *(const float4*)Sp;
        const float4 s1 = *(const float4*)(Sp + 4);
        const float sa[8] = {s0.x, s0.y, s0.z, s0.w, s1.x, s1.y, s1.z, s1.w};
        half8 out;
#pragma unroll
        for (int e = 0; e < 8; ++e) {
            const int jg = j0 + tc + e;
            out[e] = (jg <= row) ? f2h(__expf(sa[e] - mv[e])) : (_Float16)0.f;
        }
        *(half8*)(P + (size_t)b * Tt * Tt + (size_t)row * Tt + j0 + tc) = out;
    }
}

// ---------------------------------------------------------------------------
// context = P @ Vscaled.  Single-product fp16 MFMA, causal k-truncation.
// ---------------------------------------------------------------------------
__global__ __launch_bounds__(256) void context_mfma_kernel(
    const _Float16* __restrict__ P, const _Float16* __restrict__ Vt,
    float* __restrict__ Out)
{
    __shared__ _Float16 Al[8][512];
    __shared__ _Float16 Bl[8][512];

    const int bx = blockIdx.x;
    const int by = (int)gridDim.y - 1 - blockIdx.y;  // heavy q-blocks first
    const int b  = blockIdx.z;
    const int d0 = bx * 128;
    const int q0 = by * 128;
    const _Float16* Pb = P + (size_t)b * Tt * Tt;
    const _Float16* Vb = Vt + (size_t)b * Dd * Tt;
    float* Ob = Out + (size_t)b * Tt * Dd;

    const int tid = threadIdx.x;
    const int w = tid >> 6, lane = tid & 63;
    const int lr = lane & 15, lq = lane >> 4;
    const int wr = (w >> 1) * 4, wc = (w & 1) * 4;

    f32x4 acc[4][4];
#pragma unroll
    for (int i = 0; i < 4; ++i)
#pragma unroll
        for (int j = 0; j < 4; ++j)
#pragma unroll
            for (int c = 0; c < 4; ++c) acc[i][j][c] = 0.f;

    const int kmax = q0 + 128;
    for (int k0 = 0; k0 < kmax; k0 += 32) {
        __syncthreads();
#pragma unroll
        for (int s2 = 0; s2 < 2; ++s2) {
            const int s = w * 2 + s2;
            GLD16(Pb + (size_t)(q0 + s * 16 + lr) * Tt + k0 + lq * 8, &Al[s][0]);
            GLD16(Vb + (size_t)(d0 + s * 16 + lr) * Tt + k0 + lq * 8, &Bl[s][0]);
        }
        __syncthreads();
        half8 a[4], b2[4];
#pragma unroll
        for (int i = 0; i < 4; ++i) a[i] = *(const half8*)&Al[wr + i][lane * 8];
#pragma unroll
        for (int j = 0; j < 4; ++j) b2[j] = *(const half8*)&Bl[wc + j][lane * 8];
#pragma unroll
        for (int i = 0; i < 4; ++i)
#pragma unroll
            for (int j = 0; j < 4; ++j)
                acc[i][j] = __builtin_amdgcn_mfma_f32_16x16x32_f16(a[i], b2[j], acc[i][j], 0, 0, 0);
    }

#pragma unroll
    for (int i = 0; i < 4; ++i)
#pragma unroll
        for (int r = 0; r < 4; ++r) {
            const int row = q0 + (wr + i) * 16 + lq * 4 + r;
#pragma unroll
            for (int j = 0; j < 4; ++j)
                Ob[(size_t)row * Dd + d0 + (wc + j) * 16 + lr] = acc[i][j][r];
        }
}

}  // namespace

extern "C" void kernel_launch(void* const* d_in, const int* in_sizes, int n_in,
                              void* d_out, int out_size, void* d_ws, size_t ws_size,
                              hipStream_t stream)
{
    const float* X  = (const float*)d_in[0];
    const float* Wq = (const float*)d_in[1];
    const float* Wk = (const float*)d_in[2];
    const float* Wv = (const float*)d_in[3];

    char* ws = (char*)d_ws;
    const size_t MB = 1024 * 1024;
    _Float16* Xhi  = (_Float16*)ws;
    _Float16* Xlo  = (_Float16*)(ws + 16 * MB);
    _Float16* Wqh  = (_Float16*)(ws + 32 * MB);
    _Float16* Wql  = (_Float16*)(ws + 34 * MB);
    _Float16* Wkh  = (_Float16*)(ws + 36 * MB);
    _Float16* Wkl  = (_Float16*)(ws + 38 * MB);
    _Float16* WvTh = (_Float16*)(ws + 40 * MB);
    _Float16* GTh  = (_Float16*)(ws + 44 * MB);
    _Float16* GTl  = (_Float16*)(ws + 46 * MB);
    _Float16* Thi  = (_Float16*)(ws + 48 * MB);
    _Float16* Tlo  = (_Float16*)(ws + 64 * MB);
    _Float16* P    = Thi;                             // overlay after scores (32 MB)
    _Float16* Vt   = (_Float16*)(ws + 80 * MB);
    _Float16* Vrow = (_Float16*)(ws + 96 * MB);
    float*    S    = (float*)(ws + 112 * MB);         // 64 MB
    float*    Mb   = (float*)(ws + 176 * MB);
    float*    Lb   = Mb + (size_t)Bb * Tt;
    float*    Pm   = Lb + (size_t)Bb * Tt;
    float*    Pl   = Pm + (size_t)Bb * NCH * Tt;
    float*    Out  = (float*)d_out;

    convert_x_kernel<<<BT * Dd / 1024, 256, 0, stream>>>(X, Xhi, Xlo);
    convert_wqk_kernel<<<dim3(Dd * Dd / 1024, 2), 256, 0, stream>>>(Wq, Wk, Wqh, Wql, Wkh, Wkl);
    convert_wv_kernel<<<dim3(16, 16), 256, 0, stream>>>(Wv, WvTh);
    gt_kernel<<<dim3(16, 16), 256, 0, stream>>>(Wkh, Wkl, Wqh, Wql, GTh, GTl);
    t_kernel<<<dim3(8, 64), 256, 0, stream>>>(Xhi, Xlo, GTh, GTl, Thi, Tlo);
    v_kernel<<<dim3(8, 64), 256, 0, stream>>>(Xhi, WvTh, Vrow);
    scores_mfma_kernel<<<dim3(136, 1, Bb), 256, 0, stream>>>(Thi, Tlo, Xhi, Xlo, S, Pm, Pl);
    colstats_merge_kernel<<<dim3(Tt / 256, Bb), 256, 0, stream>>>(Pm, Pl, Mb, Lb);
    transpose_v_kernel<<<dim3(Dd / 64, Tt / 64, Bb), 256, 0, stream>>>(Vrow, Lb, Vt);
    pmat_kernel<<<dim3(136, 1, Bb), 256, 0, stream>>>(S, Mb, P);
    context_mfma_kernel<<<dim3(Dd / 128, Tt / 128, Bb), 256, 0, stream>>>(P, Vt, Out);
}